// Round 1
// 535.843 us; speedup vs baseline: 1.0328x; 1.0328x over previous
//
#include <hip/hip_runtime.h>

typedef __attribute__((ext_vector_type(8)))  __bf16 bf16x8;
typedef __attribute__((ext_vector_type(4)))  float  f32x4;
typedef __attribute__((ext_vector_type(8)))  unsigned short u16x8;

// ---------- fp32 -> bf16 (RNE) ----------
__device__ inline unsigned short f2bf(float f) {
    unsigned int u = __float_as_uint(f);
    u += 0x7FFFu + ((u >> 16) & 1u);
    return (unsigned short)(u >> 16);
}

// ---------- scatter-add COO directly into bf16 dense via 32-bit CAS ----------
__global__ __launch_bounds__(256) void scatter_bf16(
        const float* __restrict__ vals,
        const int* __restrict__ rows,
        const int* __restrict__ cols,
        unsigned short* __restrict__ Ab,
        int nnz, int in_f) {
    int i = blockIdx.x * blockDim.x + threadIdx.x;
    if (i >= nnz) return;
    float v = vals[i];
    size_t idx = (size_t)rows[i] * in_f + cols[i];
    unsigned int* word = (unsigned int*)(Ab + (idx & ~(size_t)1));
    unsigned int sh = (unsigned int)(idx & 1) * 16u;
    unsigned int old = *word, assumed;
    do {
        assumed = old;
        unsigned int cur = (assumed >> sh) & 0xFFFFu;
        float f = __uint_as_float(cur << 16) + v;
        unsigned int nb = f2bf(f);
        unsigned int repl = (assumed & ~(0xFFFFu << sh)) | (nb << sh);
        old = atomicCAS(word, assumed, repl);
    } while (old != assumed);
}

// ---------- fp32 -> bf16 bulk convert (weight), 8 elems/thread ----------
__global__ __launch_bounds__(256) void cvt_kernel(
        const float* __restrict__ src,
        unsigned short* __restrict__ dst,
        long n) {
    long i = ((long)blockIdx.x * blockDim.x + threadIdx.x) * 8;
    if (i + 8 <= n) {
        f32x4 a = *(const f32x4*)(src + i);
        f32x4 b = *(const f32x4*)(src + i + 4);
        u16x8 o;
        o[0] = f2bf(a[0]); o[1] = f2bf(a[1]); o[2] = f2bf(a[2]); o[3] = f2bf(a[3]);
        o[4] = f2bf(b[0]); o[5] = f2bf(b[1]); o[6] = f2bf(b[2]); o[7] = f2bf(b[3]);
        *(u16x8*)(dst + i) = o;
    }
}

// ============================================================================
// bf16 NT GEMM, 256x256 tile, BK=64, 8 waves (2M x 4N), 8-phase-class schedule
// with counted vmcnt (never drained to 0 in the main loop).
//
// LDS: sA/sB [2 dbuf][2 k-slab][256 rows][32 cols] bf16 = 128 KiB total.
// Each 16KB k-slab is staged by one phase (2 global_load_lds x 512 thr x 16B).
// Swizzle: 16B slot' = slot ^ (row&3); applied on the *global source* address
// (global_load_lds writes linearly) and on the ds_read address (rule: both
// sides or neither).
//
// Per K-tile t (4 phases, kc = p>>1, n-half = p&1), per wave:
//   p0: ds_read a[0..7](kc0) + b0,b1(kc0)  | issue A-k1(t+1)->buf[nxt]
//   p1: ds_read b2,b3(kc0)                 | issue B-k1(t+1)->buf[nxt] | vmcnt(8)
//   p2: ds_read a[0..7](kc1) + b0,b1(kc1)  | issue A-k0(t+2)->buf[cur]
//   p3: ds_read b2,b3(kc1)                 | issue B-k0(t+2)->buf[cur] | vmcnt(8)
// each phase: {reads, stage} -> s_barrier -> lgkmcnt(0) -> setprio(1) ->
// 16x mfma_f32_16x16x32_bf16 -> setprio(0) -> [vmcnt(8)] -> s_barrier.
//
// Safety invariants (checked per phase):
//  - overwrite-issue of a slab happens >=1 barrier after its last ds_read
//    (A-k0 read p0, overwritten p2; B-k0 read p0-p1, overwritten p3; k1 slabs
//    read p2-p3, overwritten next tile p0/p1).
//  - vmcnt(8) = 4 slabs in flight; every slab is issued 5-6 phases before its
//    first read, so the 8 newest loads never include a needed slab.
//  - tail tiles issue wrapped (dummy) slabs into dead regions so per-wave
//    vmcnt accounting stays uniform. Requires K/64 >= 3 (here K=4096).
// ============================================================================

__device__ __forceinline__ bf16x8 read_frag(const unsigned short* slab, int row, int g) {
    return *(const bf16x8*)(slab + row * 32 + ((g ^ (row & 3)) << 3));
}

__device__ __forceinline__ void stage_slab(const unsigned short* __restrict__ G,
                                           int grow0, int K, int kelem,
                                           unsigned short* slab, int tid) {
    const int lane = tid & 63, wv = tid >> 6;
    #pragma unroll
    for (int j = 0; j < 2; ++j) {
        int u = wv * 128 + j * 64 + lane;          // 16B-unit index 0..1023
        int row = u >> 2, slot = u & 3;
        const unsigned short* g = G + (size_t)(grow0 + row) * K
                                    + (kelem + ((slot ^ (row & 3)) << 3));
        unsigned short* l = slab + (wv * 128 + j * 64) * 8;   // wave-uniform base
        __builtin_amdgcn_global_load_lds(
            (const __attribute__((address_space(1))) void*)g,
            (__attribute__((address_space(3))) void*)l, 16, 0, 0);
    }
}

__global__ __launch_bounds__(512, 2) void gemm_bt_bias(
    const unsigned short* __restrict__ A,   // bf16 bits [M,K]
    const unsigned short* __restrict__ B,   // bf16 bits [N,K] (weight)
    const float* __restrict__ bias,         // [N]
    float* __restrict__ C,                  // [M,N]
    int M, int N, int K)
{
    __shared__ unsigned short sA[2][2][8192];   // [dbuf][kslab][256*32]
    __shared__ unsigned short sB[2][2][8192];

    const int tid  = threadIdx.x;
    const int lane = tid & 63;
    const int wave = tid >> 6;
    const int wm = (wave >> 2) * 128;      // 2 waves along M
    const int wn = (wave & 3) * 64;        // 4 waves along N
    const int r15 = lane & 15;
    const int g   = lane >> 4;

    // XCD-aware bijective remap (nwg = 512, %8 == 0)
    const int nbx = gridDim.x;
    const int nwg = gridDim.x * gridDim.y;
    int flat = blockIdx.y * gridDim.x + blockIdx.x;
    int rid = (nwg & 7) ? flat : ((flat & 7) * (nwg >> 3) + (flat >> 3));
    const int bm = (rid / nbx) * 256;
    const int bn = (rid % nbx) * 256;

    f32x4 acc[8][4];
    #pragma unroll
    for (int i = 0; i < 8; ++i)
        #pragma unroll
        for (int jg = 0; jg < 4; ++jg)
            #pragma unroll
            for (int r = 0; r < 4; ++r) acc[i][jg][r] = 0.f;

    // ---- prologue: 6 slabs (tile0 fully, tile1 k0-half) ----
    stage_slab(A, bm, K, 0,       &sA[0][0][0], tid);
    stage_slab(B, bn, K, 0,       &sB[0][0][0], tid);
    stage_slab(A, bm, K, 32,      &sA[0][1][0], tid);
    stage_slab(B, bn, K, 32,      &sB[0][1][0], tid);
    stage_slab(A, bm, K, 64,      &sA[1][0][0], tid);
    stage_slab(B, bn, K, 64,      &sB[1][0][0], tid);
    asm volatile("s_waitcnt vmcnt(8)" ::: "memory");
    __builtin_amdgcn_s_barrier();

    const int nt = K >> 6;
    for (int t = 0; t < nt; ++t) {
        const int cur = t & 1, nxt = cur ^ 1;
        const int t1k = ((t + 1 < nt) ? t + 1 : 0) << 6;
        const int t2k = ((t + 2 < nt) ? t + 2 : 0) << 6;
        const unsigned short* sAc0 = &sA[cur][0][0];
        const unsigned short* sAc1 = &sA[cur][1][0];
        const unsigned short* sBc0 = &sB[cur][0][0];
        const unsigned short* sBc1 = &sB[cur][1][0];

        bf16x8 a[8], b[2];

        // ---------------- phase 0: kc=0, n-frags 0,1 ----------------
        #pragma unroll
        for (int i = 0; i < 8; ++i) a[i] = read_frag(sAc0, wm + i * 16 + r15, g);
        b[0] = read_frag(sBc0, wn + r15, g);
        b[1] = read_frag(sBc0, wn + 16 + r15, g);
        stage_slab(A, bm, K, t1k + 32, &sA[nxt][1][0], tid);
        __builtin_amdgcn_s_barrier();
        asm volatile("s_waitcnt lgkmcnt(0)" ::: "memory");
        __builtin_amdgcn_s_setprio(1);
        #pragma unroll
        for (int i = 0; i < 8; ++i) {
            acc[i][0] = __builtin_amdgcn_mfma_f32_16x16x32_bf16(a[i], b[0], acc[i][0], 0, 0, 0);
            acc[i][1] = __builtin_amdgcn_mfma_f32_16x16x32_bf16(a[i], b[1], acc[i][1], 0, 0, 0);
        }
        __builtin_amdgcn_s_setprio(0);
        __builtin_amdgcn_s_barrier();

        // ---------------- phase 1: kc=0, n-frags 2,3 ----------------
        b[0] = read_frag(sBc0, wn + 32 + r15, g);
        b[1] = read_frag(sBc0, wn + 48 + r15, g);
        stage_slab(B, bn, K, t1k + 32, &sB[nxt][1][0], tid);
        __builtin_amdgcn_s_barrier();
        asm volatile("s_waitcnt lgkmcnt(0)" ::: "memory");
        __builtin_amdgcn_s_setprio(1);
        #pragma unroll
        for (int i = 0; i < 8; ++i) {
            acc[i][2] = __builtin_amdgcn_mfma_f32_16x16x32_bf16(a[i], b[0], acc[i][2], 0, 0, 0);
            acc[i][3] = __builtin_amdgcn_mfma_f32_16x16x32_bf16(a[i], b[1], acc[i][3], 0, 0, 0);
        }
        __builtin_amdgcn_s_setprio(0);
        asm volatile("s_waitcnt vmcnt(8)" ::: "memory");
        __builtin_amdgcn_s_barrier();

        // ---------------- phase 2: kc=1, n-frags 0,1 ----------------
        #pragma unroll
        for (int i = 0; i < 8; ++i) a[i] = read_frag(sAc1, wm + i * 16 + r15, g);
        b[0] = read_frag(sBc1, wn + r15, g);
        b[1] = read_frag(sBc1, wn + 16 + r15, g);
        stage_slab(A, bm, K, t2k, &sA[cur][0][0], tid);
        __builtin_amdgcn_s_barrier();
        asm volatile("s_waitcnt lgkmcnt(0)" ::: "memory");
        __builtin_amdgcn_s_setprio(1);
        #pragma unroll
        for (int i = 0; i < 8; ++i) {
            acc[i][0] = __builtin_amdgcn_mfma_f32_16x16x32_bf16(a[i], b[0], acc[i][0], 0, 0, 0);
            acc[i][1] = __builtin_amdgcn_mfma_f32_16x16x32_bf16(a[i], b[1], acc[i][1], 0, 0, 0);
        }
        __builtin_amdgcn_s_setprio(0);
        __builtin_amdgcn_s_barrier();

        // ---------------- phase 3: kc=1, n-frags 2,3 ----------------
        b[0] = read_frag(sBc1, wn + 32 + r15, g);
        b[1] = read_frag(sBc1, wn + 48 + r15, g);
        stage_slab(B, bn, K, t2k, &sB[cur][0][0], tid);
        __builtin_amdgcn_s_barrier();
        asm volatile("s_waitcnt lgkmcnt(0)" ::: "memory");
        __builtin_amdgcn_s_setprio(1);
        #pragma unroll
        for (int i = 0; i < 8; ++i) {
            acc[i][2] = __builtin_amdgcn_mfma_f32_16x16x32_bf16(a[i], b[0], acc[i][2], 0, 0, 0);
            acc[i][3] = __builtin_amdgcn_mfma_f32_16x16x32_bf16(a[i], b[1], acc[i][3], 0, 0, 0);
        }
        __builtin_amdgcn_s_setprio(0);
        asm volatile("s_waitcnt vmcnt(8)" ::: "memory");
        __builtin_amdgcn_s_barrier();
    }

    // ---- epilogue: C/D layout col=lane&15, row=(lane>>4)*4+r ----
    #pragma unroll
    for (int jg = 0; jg < 4; ++jg) {
        int col = bn + wn + jg * 16 + r15;
        float bv = bias[col];
        #pragma unroll
        for (int i = 0; i < 8; ++i) {
            int rbase = bm + wm + i * 16 + g * 4;
            #pragma unroll
            for (int r = 0; r < 4; ++r) {
                __builtin_nontemporal_store(acc[i][jg][r] + bv,
                                            &C[(size_t)(rbase + r) * N + col]);
            }
        }
    }
}

extern "C" void kernel_launch(void* const* d_in, const int* in_sizes, int n_in,
                              void* d_out, int out_size, void* d_ws, size_t ws_size,
                              hipStream_t stream) {
    const float* vals   = (const float*)d_in[0];
    const int*   rows   = (const int*)d_in[1];
    const int*   cols   = (const int*)d_in[2];
    const float* weight = (const float*)d_in[3];  // [OUT, IN] row-major
    const float* bias   = (const float*)d_in[4];

    const int NNZ = in_sizes[0];
    const int OUT = in_sizes[4];
    const int IN  = in_sizes[3] / OUT;
    const int M   = out_size / OUT;     // n_rows

    // workspace layout: Ab bf16 [M,IN] | Wb bf16 [OUT,IN]
    unsigned short* Ab = (unsigned short*)d_ws;
    size_t abBytes = (size_t)M * IN * sizeof(unsigned short);
    unsigned short* Wb = (unsigned short*)((char*)d_ws + abBytes);

    // 1) zero bf16 dense (bf16 zero == 0x0000)
    hipMemsetAsync(Ab, 0, abBytes, stream);

    // 2) scatter-add COO directly into bf16 (CAS; duplicates accumulate)
    scatter_bf16<<<(NNZ + 255) / 256, 256, 0, stream>>>(vals, rows, cols, Ab, NNZ, IN);

    // 3) convert weight to bf16
    {
        long nW = (long)OUT * IN;
        cvt_kernel<<<(int)((nW / 8 + 255) / 256), 256, 0, stream>>>(weight, Wb, nW);
    }

    // 4) GEMM + bias (256x256 tiles, 512 threads)
    dim3 grid(OUT / 256, M / 256);   // 16 x 32 = 512 blocks
    gemm_bt_bias<<<grid, 512, 0, stream>>>(Ab, Wb, bias, (float*)d_out, M, OUT, IN);
}

// Round 3
// 528.927 us; speedup vs baseline: 1.0463x; 1.0131x over previous
//
#include <hip/hip_runtime.h>

typedef __attribute__((ext_vector_type(8)))  __bf16 bf16x8;
typedef __attribute__((ext_vector_type(4)))  float  f32x4;
typedef __attribute__((ext_vector_type(8)))  unsigned short u16x8;

// ---------- fp32 -> bf16 (RNE) ----------
__device__ inline unsigned short f2bf(float f) {
    unsigned int u = __float_as_uint(f);
    u += 0x7FFFu + ((u >> 16) & 1u);
    return (unsigned short)(u >> 16);
}

// ============================================================================
// Fused scatter (COO -> bf16 dense) + weight fp32->bf16 convert.
// Scatter uses global_atomic_pk_add_bf16 when available (single fire-and-
// forget HW atomic, no CAS retry loop, no read-back latency); CAS fallback
// preserves compile safety.  For singleton (row,col) — the overwhelmingly
// common case — both paths store round_bf16(v): numerics identical.
// cvt (BW-bound) and scatter (latency-bound) share one launch so they overlap.
// ============================================================================
__global__ __launch_bounds__(256) void scatter_cvt(
        const float* __restrict__ vals,
        const int* __restrict__ rows,
        const int* __restrict__ cols,
        unsigned short* __restrict__ Ab,
        int nnz, int in_f,
        const float* __restrict__ wsrc,
        unsigned short* __restrict__ wdst,
        long nW, int cvtBlocks) {
    if ((int)blockIdx.x < cvtBlocks) {
        long i = ((long)blockIdx.x * 256 + threadIdx.x) * 8;
        if (i + 8 <= nW) {
            f32x4 a = *(const f32x4*)(wsrc + i);
            f32x4 b = *(const f32x4*)(wsrc + i + 4);
            u16x8 o;
            o[0] = f2bf(a[0]); o[1] = f2bf(a[1]); o[2] = f2bf(a[2]); o[3] = f2bf(a[3]);
            o[4] = f2bf(b[0]); o[5] = f2bf(b[1]); o[6] = f2bf(b[2]); o[7] = f2bf(b[3]);
            *(u16x8*)(wdst + i) = o;
        }
        return;
    }
    int i = ((int)blockIdx.x - cvtBlocks) * 256 + threadIdx.x;
    if (i >= nnz) return;
    float v = vals[i];
    size_t idx = (size_t)rows[i] * in_f + cols[i];
#if __has_builtin(__builtin_amdgcn_global_atomic_fadd_v2bf16)
    typedef __attribute__((ext_vector_type(2))) short s16x2;
    unsigned short hv = f2bf(v);
    s16x2 add;
    add[0] = (idx & 1) ? (short)0 : (short)hv;
    add[1] = (idx & 1) ? (short)hv : (short)0;
    __builtin_amdgcn_global_atomic_fadd_v2bf16(
        (__attribute__((address_space(1))) s16x2*)(Ab + (idx & ~(size_t)1)), add);
#else
    unsigned int* word = (unsigned int*)(Ab + (idx & ~(size_t)1));
    unsigned int sh = (unsigned int)(idx & 1) * 16u;
    unsigned int old = *word, assumed;
    do {
        assumed = old;
        unsigned int cur = (assumed >> sh) & 0xFFFFu;
        float f = __uint_as_float(cur << 16) + v;
        unsigned int nb = f2bf(f);
        unsigned int repl = (assumed & ~(0xFFFFu << sh)) | (nb << sh);
        old = atomicCAS(word, assumed, repl);
    } while (old != assumed);
#endif
}

// ============================================================================
// bf16 NT GEMM, 256x256 tile, BK=64, 8 waves (2M x 4N), 4 phases per K-tile,
// counted vmcnt (never 0 in-loop).
//
// LDS geometry = m201's proven layout: per operand, per dbuf, two row-halves
// of [128 rows][64 cols] bf16 (128 B rows).  st_16x32 swizzle: 16B-slot index
// c' = c ^ (((row>>2)&1)<<1)  == byte bit5 ^= bit9 (bit-identical to m201).
// global_load_lds writes linearly (wave-uniform base + lane*16), so the
// swizzle is applied by permuting the per-lane GLOBAL source address;
// ds_read applies the same involution (both-sides rule, m228c/m231).
//
// Schedule per K-tile t (phase = (kc, n-half)):
//   p0: read A(chunk0) x8 + B jg0,1(chunk0) | stage B(t+1) h0+h1 -> B[nxt]
//   p1: read B jg2,3(chunk0)
//   p2: read A(chunk1) x8 + B jg0,1(chunk1)
//   p3: read B jg2,3(chunk1)                | stage A(t+2) h0+h1 -> A[cur]
// Each phase: {ds_reads, stage} -> s_barrier -> lgkmcnt(0) -> sched_barrier(0)
// -> setprio(1) -> 16x mfma_f32_16x16x32_bf16 -> setprio(0) -> [vmcnt(4) @p3]
// -> s_barrier.
//
// Hazards (collective, all waves):
//  - A[cur] last read at p2 (drained per-wave by p2 lgkmcnt(0), collectively
//    by p2's end barrier) => p3's stage of A(t+2) into A[cur] is safe.
//    B[nxt] last read at t-1.p3 (same drain) => t.p0's stage is safe.
//  - FIFO vmcnt: at t.p3, outstanding = A(t+1)4 + B(t+1)4 + A(t+2)4;
//    vmcnt(4) drains A(t+1)+B(t+1) (everything t+1.p0 reads), leaving only
//    A(t+2) in flight.  Never drained to 0 in-loop.
//  - Tail tiles stage wrapped dummy slabs (never read) to keep counts
//    uniform; vmcnt(0) after the loop drains them before LDS reuse ends.
// ============================================================================

__device__ __forceinline__ bf16x8 read_frag(const unsigned short* hb, int rowl, int c) {
    int cs = c ^ ((rowl >> 1) & 2);          // ^= (row bit2) << 1
    return *(const bf16x8*)(hb + rowl * 64 + (cs << 3));
}

__device__ __forceinline__ void stage_half(const unsigned short* __restrict__ G,
                                           int grow0, int K, int kbase,
                                           unsigned short* hb, int tid) {
    const int lane = tid & 63, wv = tid >> 6;
    #pragma unroll
    for (int j = 0; j < 2; ++j) {
        int u = j * 512 + wv * 64 + lane;            // 16B-unit 0..1023
        int rowl = u >> 3;
        int c = (u & 7) ^ ((u >> 4) & 2);            // inverse swizzle on source
        const unsigned short* g = G + (size_t)(grow0 + rowl) * K + kbase + c * 8;
        unsigned short* l = hb + (size_t)(j * 512 + wv * 64) * 8;  // wave-uniform
        __builtin_amdgcn_global_load_lds(
            (const __attribute__((address_space(1))) void*)g,
            (__attribute__((address_space(3))) void*)l, 16, 0, 0);
    }
}

__global__ __launch_bounds__(512, 2) void gemm_bt_bias(
    const unsigned short* __restrict__ A,   // bf16 bits [M,K]
    const unsigned short* __restrict__ B,   // bf16 bits [N,K] (weight)
    const float* __restrict__ bias,         // [N]
    float* __restrict__ C,                  // [M,N]
    int M, int N, int K)
{
    __shared__ unsigned short sA[2][2][8192];   // [dbuf][row-half][128*64]
    __shared__ unsigned short sB[2][2][8192];

    const int tid  = threadIdx.x;
    const int lane = tid & 63;
    const int wave = tid >> 6;
    const int wm = (wave >> 2) * 128;      // 2 waves along M
    const int wn = (wave & 3) * 64;        // 4 waves along N
    const int r15 = lane & 15;
    const int g   = lane >> 4;
    const int ah  = wm >> 7;               // wave's A row-half
    const int bh  = wn >> 7;               // wave's B row-half
    const int bro = wn & 64;               // row offset within B half

    // XCD-aware bijective remap (nwg = 512, %8 == 0)
    const int nbx = gridDim.x;
    const int nwg = gridDim.x * gridDim.y;
    int flat = blockIdx.y * gridDim.x + blockIdx.x;
    int rid = (nwg & 7) ? flat : ((flat & 7) * (nwg >> 3) + (flat >> 3));
    const int bm = (rid / nbx) * 256;
    const int bn = (rid % nbx) * 256;

    f32x4 acc[8][4];
    #pragma unroll
    for (int i = 0; i < 8; ++i)
        #pragma unroll
        for (int jg = 0; jg < 4; ++jg)
            #pragma unroll
            for (int r = 0; r < 4; ++r) acc[i][jg][r] = 0.f;

    // ---- prologue: A(0), B(0), A(1) ----
    stage_half(A, bm,       K, 0,  &sA[0][0][0], tid);
    stage_half(A, bm + 128, K, 0,  &sA[0][1][0], tid);
    stage_half(B, bn,       K, 0,  &sB[0][0][0], tid);
    stage_half(B, bn + 128, K, 0,  &sB[0][1][0], tid);
    stage_half(A, bm,       K, 64, &sA[1][0][0], tid);
    stage_half(A, bm + 128, K, 64, &sA[1][1][0], tid);
    asm volatile("s_waitcnt vmcnt(4)" ::: "memory");
    __builtin_amdgcn_s_barrier();

    const int nt = K >> 6;
    for (int t = 0; t < nt; ++t) {
        const int cur = t & 1, nxt = cur ^ 1;
        const int t1k = ((t + 1 < nt) ? t + 1 : 0) << 6;
        const int t2k = ((t + 2 < nt) ? t + 2 : 0) << 6;
        const unsigned short* sAh = &sA[cur][ah][0];
        const unsigned short* sBh = &sB[cur][bh][0];

        bf16x8 a[8], b0, b1;

        // ---------------- phase 0: chunk0, B jg 0,1 ----------------
        #pragma unroll
        for (int i = 0; i < 8; ++i) a[i] = read_frag(sAh, i * 16 + r15, g);
        b0 = read_frag(sBh, bro + r15, g);
        b1 = read_frag(sBh, bro + 16 + r15, g);
        stage_half(B, bn,       K, t1k, &sB[nxt][0][0], tid);
        stage_half(B, bn + 128, K, t1k, &sB[nxt][1][0], tid);
        __builtin_amdgcn_s_barrier();
        asm volatile("s_waitcnt lgkmcnt(0)" ::: "memory");
        __builtin_amdgcn_sched_barrier(0);
        __builtin_amdgcn_s_setprio(1);
        #pragma unroll
        for (int i = 0; i < 8; ++i) {
            acc[i][0] = __builtin_amdgcn_mfma_f32_16x16x32_bf16(a[i], b0, acc[i][0], 0, 0, 0);
            acc[i][1] = __builtin_amdgcn_mfma_f32_16x16x32_bf16(a[i], b1, acc[i][1], 0, 0, 0);
        }
        __builtin_amdgcn_s_setprio(0);
        __builtin_amdgcn_s_barrier();

        // ---------------- phase 1: chunk0, B jg 2,3 ----------------
        b0 = read_frag(sBh, bro + 32 + r15, g);
        b1 = read_frag(sBh, bro + 48 + r15, g);
        __builtin_amdgcn_s_barrier();
        asm volatile("s_waitcnt lgkmcnt(0)" ::: "memory");
        __builtin_amdgcn_sched_barrier(0);
        __builtin_amdgcn_s_setprio(1);
        #pragma unroll
        for (int i = 0; i < 8; ++i) {
            acc[i][2] = __builtin_amdgcn_mfma_f32_16x16x32_bf16(a[i], b0, acc[i][2], 0, 0, 0);
            acc[i][3] = __builtin_amdgcn_mfma_f32_16x16x32_bf16(a[i], b1, acc[i][3], 0, 0, 0);
        }
        __builtin_amdgcn_s_setprio(0);
        __builtin_amdgcn_s_barrier();

        // ---------------- phase 2: chunk1, B jg 0,1 ----------------
        #pragma unroll
        for (int i = 0; i < 8; ++i) a[i] = read_frag(sAh, i * 16 + r15, 4 + g);
        b0 = read_frag(sBh, bro + r15, 4 + g);
        b1 = read_frag(sBh, bro + 16 + r15, 4 + g);
        __builtin_amdgcn_s_barrier();
        asm volatile("s_waitcnt lgkmcnt(0)" ::: "memory");
        __builtin_amdgcn_sched_barrier(0);
        __builtin_amdgcn_s_setprio(1);
        #pragma unroll
        for (int i = 0; i < 8; ++i) {
            acc[i][0] = __builtin_amdgcn_mfma_f32_16x16x32_bf16(a[i], b0, acc[i][0], 0, 0, 0);
            acc[i][1] = __builtin_amdgcn_mfma_f32_16x16x32_bf16(a[i], b1, acc[i][1], 0, 0, 0);
        }
        __builtin_amdgcn_s_setprio(0);
        __builtin_amdgcn_s_barrier();

        // ---------------- phase 3: chunk1, B jg 2,3 ----------------
        b0 = read_frag(sBh, bro + 32 + r15, 4 + g);
        b1 = read_frag(sBh, bro + 48 + r15, 4 + g);
        stage_half(A, bm,       K, t2k, &sA[cur][0][0], tid);
        stage_half(A, bm + 128, K, t2k, &sA[cur][1][0], tid);
        __builtin_amdgcn_s_barrier();
        asm volatile("s_waitcnt lgkmcnt(0)" ::: "memory");
        __builtin_amdgcn_sched_barrier(0);
        __builtin_amdgcn_s_setprio(1);
        #pragma unroll
        for (int i = 0; i < 8; ++i) {
            acc[i][2] = __builtin_amdgcn_mfma_f32_16x16x32_bf16(a[i], b0, acc[i][2], 0, 0, 0);
            acc[i][3] = __builtin_amdgcn_mfma_f32_16x16x32_bf16(a[i], b1, acc[i][3], 0, 0, 0);
        }
        __builtin_amdgcn_s_setprio(0);
        asm volatile("s_waitcnt vmcnt(4)" ::: "memory");
        __builtin_amdgcn_s_barrier();
    }
    asm volatile("s_waitcnt vmcnt(0)" ::: "memory");   // drain dummy tail DMAs

    // ---- epilogue: C/D layout col=lane&15, row=(lane>>4)*4+r ----
    #pragma unroll
    for (int jg = 0; jg < 4; ++jg) {
        int col = bn + wn + jg * 16 + r15;
        float bv = bias[col];
        #pragma unroll
        for (int i = 0; i < 8; ++i) {
            int rbase = bm + wm + i * 16 + g * 4;
            #pragma unroll
            for (int r = 0; r < 4; ++r) {
                __builtin_nontemporal_store(acc[i][jg][r] + bv,
                                            &C[(size_t)(rbase + r) * N + col]);
            }
        }
    }
}

extern "C" void kernel_launch(void* const* d_in, const int* in_sizes, int n_in,
                              void* d_out, int out_size, void* d_ws, size_t ws_size,
                              hipStream_t stream) {
    const float* vals   = (const float*)d_in[0];
    const int*   rows   = (const int*)d_in[1];
    const int*   cols   = (const int*)d_in[2];
    const float* weight = (const float*)d_in[3];  // [OUT, IN] row-major
    const float* bias   = (const float*)d_in[4];

    const int NNZ = in_sizes[0];
    const int OUT = in_sizes[4];
    const int IN  = in_sizes[3] / OUT;
    const int M   = out_size / OUT;     // n_rows

    // workspace layout: Ab bf16 [M,IN] | Wb bf16 [OUT,IN]
    unsigned short* Ab = (unsigned short*)d_ws;
    size_t abBytes = (size_t)M * IN * sizeof(unsigned short);
    unsigned short* Wb = (unsigned short*)((char*)d_ws + abBytes);

    // 1) zero bf16 dense (bf16 zero == 0x0000)
    hipMemsetAsync(Ab, 0, abBytes, stream);

    // 2+3) fused scatter-add (pk_add_bf16) + weight convert
    {
        long nW = (long)OUT * IN;
        int cvtBlocks = (int)((nW / 8 + 255) / 256);
        int scBlocks  = (NNZ + 255) / 256;
        scatter_cvt<<<cvtBlocks + scBlocks, 256, 0, stream>>>(
            vals, rows, cols, Ab, NNZ, IN, weight, Wb, nW, cvtBlocks);
    }

    // 4) GEMM + bias (256x256 tiles, 512 threads)
    dim3 grid(OUT / 256, M / 256);   // 16 x 32 = 512 blocks
    gemm_bt_bias<<<grid, 512, 0, stream>>>(Ab, Wb, bias, (float*)d_out, M, OUT, IN);
}

// Round 4
// 513.358 us; speedup vs baseline: 1.0781x; 1.0303x over previous
//
#include <hip/hip_runtime.h>

typedef __attribute__((ext_vector_type(8)))  __bf16 bf16x8;
typedef __attribute__((ext_vector_type(4)))  float  f32x4;
typedef __attribute__((ext_vector_type(8)))  unsigned short u16x8;

// ---------- fp32 -> bf16 (RNE) ----------
__device__ inline unsigned short f2bf(float f) {
    unsigned int u = __float_as_uint(f);
    u += 0x7FFFu + ((u >> 16) & 1u);
    return (unsigned short)(u >> 16);
}

// ============================================================================
// Fused scatter (COO -> bf16 dense) + weight fp32->bf16 convert.
// ============================================================================
__global__ __launch_bounds__(256) void scatter_cvt(
        const float* __restrict__ vals,
        const int* __restrict__ rows,
        const int* __restrict__ cols,
        unsigned short* __restrict__ Ab,
        int nnz, int in_f,
        const float* __restrict__ wsrc,
        unsigned short* __restrict__ wdst,
        long nW, int cvtBlocks) {
    if ((int)blockIdx.x < cvtBlocks) {
        long i = ((long)blockIdx.x * 256 + threadIdx.x) * 8;
        if (i + 8 <= nW) {
            f32x4 a = *(const f32x4*)(wsrc + i);
            f32x4 b = *(const f32x4*)(wsrc + i + 4);
            u16x8 o;
            o[0] = f2bf(a[0]); o[1] = f2bf(a[1]); o[2] = f2bf(a[2]); o[3] = f2bf(a[3]);
            o[4] = f2bf(b[0]); o[5] = f2bf(b[1]); o[6] = f2bf(b[2]); o[7] = f2bf(b[3]);
            *(u16x8*)(wdst + i) = o;
        }
        return;
    }
    int i = ((int)blockIdx.x - cvtBlocks) * 256 + threadIdx.x;
    if (i >= nnz) return;
    float v = vals[i];
    size_t idx = (size_t)rows[i] * in_f + cols[i];
#if __has_builtin(__builtin_amdgcn_global_atomic_fadd_v2bf16)
    typedef __attribute__((ext_vector_type(2))) short s16x2;
    unsigned short hv = f2bf(v);
    s16x2 add;
    add[0] = (idx & 1) ? (short)0 : (short)hv;
    add[1] = (idx & 1) ? (short)hv : (short)0;
    __builtin_amdgcn_global_atomic_fadd_v2bf16(
        (__attribute__((address_space(1))) s16x2*)(Ab + (idx & ~(size_t)1)), add);
#else
    unsigned int* word = (unsigned int*)(Ab + (idx & ~(size_t)1));
    unsigned int sh = (unsigned int)(idx & 1) * 16u;
    unsigned int old = *word, assumed;
    do {
        assumed = old;
        unsigned int cur = (assumed >> sh) & 0xFFFFu;
        float f = __uint_as_float(cur << 16) + v;
        unsigned int nb = f2bf(f);
        unsigned int repl = (assumed & ~(0xFFFFu << sh)) | (nb << sh);
        old = atomicCAS(word, assumed, repl);
    } while (old != assumed);
#endif
}

// ============================================================================
// bf16 NT GEMM, 256x256 tile, BK=64, 8 waves (2M x 4N), 4 phases per K-tile,
// counted vmcnt (never 0 in-loop).
//
// LDS: per operand, per dbuf, two row-halves of [128 rows][64 cols] bf16
// (128 B rows, 8 x 16B slots per row).
//
// SWIZZLE (R3 post-mortem fix): with a 128 B row stride, bankquad(row,slot) =
// (row*8 + slot) mod 8 = slot — the row contributes NOTHING, so a 1-bit XOR
// (R3) spread 16 rows over only 2 of 8 bank-quads -> 4-way conflict (25.2M
// counter, ~4 extra cyc per ds_read_b128).  Correct fix per G4's [rows][128B]
// case: 3-bit XOR, slot' = slot ^ (row&7).  Then an 8-lane read group (rows
// r..r+7, fixed slot g) hits quads g^{0..7} — all 8 distinct; 16-lane
// grouping gives 2 lanes/bank which is free (m136).  Applied on the global
// SOURCE address (global_load_lds writes linearly) + on the ds_read address
// (both-sides involution, m228c/m231).
//
// Schedule per K-tile t (phase = (kc, n-half)):
//   p0: read A(chunk0) x8 + B jg0,1(chunk0) | stage B(t+1) h0+h1 -> B[nxt]
//   p1: read B jg2,3(chunk0)
//   p2: read A(chunk1) x8 + B jg0,1(chunk1)
//   p3: read B jg2,3(chunk1)                | stage A(t+2) h0+h1 -> A[cur]
// Each phase: {ds_reads, stage} -> s_barrier -> lgkmcnt(0) -> sched_barrier(0)
// -> setprio(1) -> 16x mfma_f32_16x16x32_bf16 -> setprio(0) -> [vmcnt(4) @p3]
// -> s_barrier.   Hazard/FIFO accounting unchanged from R3 (verified).
// ============================================================================

__device__ __forceinline__ bf16x8 read_frag(const unsigned short* hb, int rowl, int c) {
    int cs = c ^ (rowl & 7);                 // 3-bit XOR: all 8 bank-quads
    return *(const bf16x8*)(hb + rowl * 64 + (cs << 3));
}

__device__ __forceinline__ void stage_half(const unsigned short* __restrict__ G,
                                           int grow0, int K, int kbase,
                                           unsigned short* hb, int tid) {
    const int lane = tid & 63, wv = tid >> 6;
    #pragma unroll
    for (int j = 0; j < 2; ++j) {
        int u = j * 512 + wv * 64 + lane;            // 16B-unit 0..1023
        int rowl = u >> 3;
        int c = (u & 7) ^ (rowl & 7);                // inverse swizzle on source
        const unsigned short* g = G + (size_t)(grow0 + rowl) * K + kbase + c * 8;
        unsigned short* l = hb + (size_t)(j * 512 + wv * 64) * 8;  // wave-uniform
        __builtin_amdgcn_global_load_lds(
            (const __attribute__((address_space(1))) void*)g,
            (__attribute__((address_space(3))) void*)l, 16, 0, 0);
    }
}

__global__ __launch_bounds__(512, 2) void gemm_bt_bias(
    const unsigned short* __restrict__ A,   // bf16 bits [M,K]
    const unsigned short* __restrict__ B,   // bf16 bits [N,K] (weight)
    const float* __restrict__ bias,         // [N]
    float* __restrict__ C,                  // [M,N]
    int M, int N, int K)
{
    __shared__ unsigned short sA[2][2][8192];   // [dbuf][row-half][128*64]
    __shared__ unsigned short sB[2][2][8192];

    const int tid  = threadIdx.x;
    const int lane = tid & 63;
    const int wave = tid >> 6;
    const int wm = (wave >> 2) * 128;      // 2 waves along M
    const int wn = (wave & 3) * 64;        // 4 waves along N
    const int r15 = lane & 15;
    const int g   = lane >> 4;
    const int ah  = wm >> 7;               // wave's A row-half
    const int bh  = wn >> 7;               // wave's B row-half
    const int bro = wn & 64;               // row offset within B half

    // XCD-aware bijective remap (nwg = 512, %8 == 0)
    const int nbx = gridDim.x;
    const int nwg = gridDim.x * gridDim.y;
    int flat = blockIdx.y * gridDim.x + blockIdx.x;
    int rid = (nwg & 7) ? flat : ((flat & 7) * (nwg >> 3) + (flat >> 3));
    const int bm = (rid / nbx) * 256;
    const int bn = (rid % nbx) * 256;

    f32x4 acc[8][4];
    #pragma unroll
    for (int i = 0; i < 8; ++i)
        #pragma unroll
        for (int jg = 0; jg < 4; ++jg)
            #pragma unroll
            for (int r = 0; r < 4; ++r) acc[i][jg][r] = 0.f;

    // ---- prologue: A(0), B(0), A(1) ----
    stage_half(A, bm,       K, 0,  &sA[0][0][0], tid);
    stage_half(A, bm + 128, K, 0,  &sA[0][1][0], tid);
    stage_half(B, bn,       K, 0,  &sB[0][0][0], tid);
    stage_half(B, bn + 128, K, 0,  &sB[0][1][0], tid);
    stage_half(A, bm,       K, 64, &sA[1][0][0], tid);
    stage_half(A, bm + 128, K, 64, &sA[1][1][0], tid);
    asm volatile("s_waitcnt vmcnt(4)" ::: "memory");
    __builtin_amdgcn_s_barrier();

    const int nt = K >> 6;
    for (int t = 0; t < nt; ++t) {
        const int cur = t & 1, nxt = cur ^ 1;
        const int t1k = ((t + 1 < nt) ? t + 1 : 0) << 6;
        const int t2k = ((t + 2 < nt) ? t + 2 : 0) << 6;
        const unsigned short* sAh = &sA[cur][ah][0];
        const unsigned short* sBh = &sB[cur][bh][0];

        bf16x8 a[8], b0, b1;

        // ---------------- phase 0: chunk0, B jg 0,1 ----------------
        #pragma unroll
        for (int i = 0; i < 8; ++i) a[i] = read_frag(sAh, i * 16 + r15, g);
        b0 = read_frag(sBh, bro + r15, g);
        b1 = read_frag(sBh, bro + 16 + r15, g);
        stage_half(B, bn,       K, t1k, &sB[nxt][0][0], tid);
        stage_half(B, bn + 128, K, t1k, &sB[nxt][1][0], tid);
        __builtin_amdgcn_s_barrier();
        asm volatile("s_waitcnt lgkmcnt(0)" ::: "memory");
        __builtin_amdgcn_sched_barrier(0);
        __builtin_amdgcn_s_setprio(1);
        #pragma unroll
        for (int i = 0; i < 8; ++i) {
            acc[i][0] = __builtin_amdgcn_mfma_f32_16x16x32_bf16(a[i], b0, acc[i][0], 0, 0, 0);
            acc[i][1] = __builtin_amdgcn_mfma_f32_16x16x32_bf16(a[i], b1, acc[i][1], 0, 0, 0);
        }
        __builtin_amdgcn_s_setprio(0);
        __builtin_amdgcn_s_barrier();

        // ---------------- phase 1: chunk0, B jg 2,3 ----------------
        b0 = read_frag(sBh, bro + 32 + r15, g);
        b1 = read_frag(sBh, bro + 48 + r15, g);
        __builtin_amdgcn_s_barrier();
        asm volatile("s_waitcnt lgkmcnt(0)" ::: "memory");
        __builtin_amdgcn_sched_barrier(0);
        __builtin_amdgcn_s_setprio(1);
        #pragma unroll
        for (int i = 0; i < 8; ++i) {
            acc[i][2] = __builtin_amdgcn_mfma_f32_16x16x32_bf16(a[i], b0, acc[i][2], 0, 0, 0);
            acc[i][3] = __builtin_amdgcn_mfma_f32_16x16x32_bf16(a[i], b1, acc[i][3], 0, 0, 0);
        }
        __builtin_amdgcn_s_setprio(0);
        __builtin_amdgcn_s_barrier();

        // ---------------- phase 2: chunk1, B jg 0,1 ----------------
        #pragma unroll
        for (int i = 0; i < 8; ++i) a[i] = read_frag(sAh, i * 16 + r15, 4 + g);
        b0 = read_frag(sBh, bro + r15, 4 + g);
        b1 = read_frag(sBh, bro + 16 + r15, 4 + g);
        __builtin_amdgcn_s_barrier();
        asm volatile("s_waitcnt lgkmcnt(0)" ::: "memory");
        __builtin_amdgcn_sched_barrier(0);
        __builtin_amdgcn_s_setprio(1);
        #pragma unroll
        for (int i = 0; i < 8; ++i) {
            acc[i][0] = __builtin_amdgcn_mfma_f32_16x16x32_bf16(a[i], b0, acc[i][0], 0, 0, 0);
            acc[i][1] = __builtin_amdgcn_mfma_f32_16x16x32_bf16(a[i], b1, acc[i][1], 0, 0, 0);
        }
        __builtin_amdgcn_s_setprio(0);
        __builtin_amdgcn_s_barrier();

        // ---------------- phase 3: chunk1, B jg 2,3 ----------------
        b0 = read_frag(sBh, bro + 32 + r15, 4 + g);
        b1 = read_frag(sBh, bro + 48 + r15, 4 + g);
        stage_half(A, bm,       K, t2k, &sA[cur][0][0], tid);
        stage_half(A, bm + 128, K, t2k, &sA[cur][1][0], tid);
        __builtin_amdgcn_s_barrier();
        asm volatile("s_waitcnt lgkmcnt(0)" ::: "memory");
        __builtin_amdgcn_sched_barrier(0);
        __builtin_amdgcn_s_setprio(1);
        #pragma unroll
        for (int i = 0; i < 8; ++i) {
            acc[i][2] = __builtin_amdgcn_mfma_f32_16x16x32_bf16(a[i], b0, acc[i][2], 0, 0, 0);
            acc[i][3] = __builtin_amdgcn_mfma_f32_16x16x32_bf16(a[i], b1, acc[i][3], 0, 0, 0);
        }
        __builtin_amdgcn_s_setprio(0);
        asm volatile("s_waitcnt vmcnt(4)" ::: "memory");
        __builtin_amdgcn_s_barrier();
    }
    asm volatile("s_waitcnt vmcnt(0)" ::: "memory");   // drain dummy tail DMAs

    // ---- epilogue: C/D layout col=lane&15, row=(lane>>4)*4+r ----
    #pragma unroll
    for (int jg = 0; jg < 4; ++jg) {
        int col = bn + wn + jg * 16 + r15;
        float bv = bias[col];
        #pragma unroll
        for (int i = 0; i < 8; ++i) {
            int rbase = bm + wm + i * 16 + g * 4;
            #pragma unroll
            for (int r = 0; r < 4; ++r) {
                __builtin_nontemporal_store(acc[i][jg][r] + bv,
                                            &C[(size_t)(rbase + r) * N + col]);
            }
        }
    }
}

extern "C" void kernel_launch(void* const* d_in, const int* in_sizes, int n_in,
                              void* d_out, int out_size, void* d_ws, size_t ws_size,
                              hipStream_t stream) {
    const float* vals   = (const float*)d_in[0];
    const int*   rows   = (const int*)d_in[1];
    const int*   cols   = (const int*)d_in[2];
    const float* weight = (const float*)d_in[3];  // [OUT, IN] row-major
    const float* bias   = (const float*)d_in[4];

    const int NNZ = in_sizes[0];
    const int OUT = in_sizes[4];
    const int IN  = in_sizes[3] / OUT;
    const int M   = out_size / OUT;     // n_rows

    // workspace layout: Ab bf16 [M,IN] | Wb bf16 [OUT,IN]
    unsigned short* Ab = (unsigned short*)d_ws;
    size_t abBytes = (size_t)M * IN * sizeof(unsigned short);
    unsigned short* Wb = (unsigned short*)((char*)d_ws + abBytes);

    // 1) zero bf16 dense (bf16 zero == 0x0000)
    hipMemsetAsync(Ab, 0, abBytes, stream);

    // 2+3) fused scatter-add (pk_add_bf16) + weight convert
    {
        long nW = (long)OUT * IN;
        int cvtBlocks = (int)((nW / 8 + 255) / 256);
        int scBlocks  = (NNZ + 255) / 256;
        scatter_cvt<<<cvtBlocks + scBlocks, 256, 0, stream>>>(
            vals, rows, cols, Ab, NNZ, IN, weight, Wb, nW, cvtBlocks);
    }

    // 4) GEMM + bias (256x256 tiles, 512 threads)
    dim3 grid(OUT / 256, M / 256);   // 16 x 32 = 512 blocks
    gemm_bt_bias<<<grid, 512, 0, stream>>>(Ab, Wb, bias, (float*)d_out, M, OUT, IN);
}

// Round 5
// 487.527 us; speedup vs baseline: 1.1352x; 1.0530x over previous
//
#include <hip/hip_runtime.h>

typedef __attribute__((ext_vector_type(8)))  __bf16 bf16x8;
typedef __attribute__((ext_vector_type(16))) float  f32x16;
typedef __attribute__((ext_vector_type(4)))  float  f32x4;
typedef __attribute__((ext_vector_type(8)))  unsigned short u16x8;

// ---------- fp32 -> bf16 (RNE) ----------
__device__ inline unsigned short f2bf(float f) {
    unsigned int u = __float_as_uint(f);
    u += 0x7FFFu + ((u >> 16) & 1u);
    return (unsigned short)(u >> 16);
}

// ============================================================================
// Fused scatter (COO -> bf16 dense) + weight fp32->bf16 convert. (unchanged)
// ============================================================================
__global__ __launch_bounds__(256) void scatter_cvt(
        const float* __restrict__ vals,
        const int* __restrict__ rows,
        const int* __restrict__ cols,
        unsigned short* __restrict__ Ab,
        int nnz, int in_f,
        const float* __restrict__ wsrc,
        unsigned short* __restrict__ wdst,
        long nW, int cvtBlocks) {
    if ((int)blockIdx.x < cvtBlocks) {
        long i = ((long)blockIdx.x * 256 + threadIdx.x) * 8;
        if (i + 8 <= nW) {
            f32x4 a = *(const f32x4*)(wsrc + i);
            f32x4 b = *(const f32x4*)(wsrc + i + 4);
            u16x8 o;
            o[0] = f2bf(a[0]); o[1] = f2bf(a[1]); o[2] = f2bf(a[2]); o[3] = f2bf(a[3]);
            o[4] = f2bf(b[0]); o[5] = f2bf(b[1]); o[6] = f2bf(b[2]); o[7] = f2bf(b[3]);
            *(u16x8*)(wdst + i) = o;
        }
        return;
    }
    int i = ((int)blockIdx.x - cvtBlocks) * 256 + threadIdx.x;
    if (i >= nnz) return;
    float v = vals[i];
    size_t idx = (size_t)rows[i] * in_f + cols[i];
#if __has_builtin(__builtin_amdgcn_global_atomic_fadd_v2bf16)
    typedef __attribute__((ext_vector_type(2))) short s16x2;
    unsigned short hv = f2bf(v);
    s16x2 add;
    add[0] = (idx & 1) ? (short)0 : (short)hv;
    add[1] = (idx & 1) ? (short)hv : (short)0;
    __builtin_amdgcn_global_atomic_fadd_v2bf16(
        (__attribute__((address_space(1))) s16x2*)(Ab + (idx & ~(size_t)1)), add);
#else
    unsigned int* word = (unsigned int*)(Ab + (idx & ~(size_t)1));
    unsigned int sh = (unsigned int)(idx & 1) * 16u;
    unsigned int old = *word, assumed;
    do {
        assumed = old;
        unsigned int cur = (assumed >> sh) & 0xFFFFu;
        float f = __uint_as_float(cur << 16) + v;
        unsigned int nb = f2bf(f);
        unsigned int repl = (assumed & ~(0xFFFFu << sh)) | (nb << sh);
        old = atomicCAS(word, assumed, repl);
    } while (old != assumed);
#endif
}

// ============================================================================
// bf16 NT GEMM, 256x256 tile, BK=64, 8 waves (2M x 4N), 32x32x16 MFMA,
// 2 phases per K-tile, ONE barrier per K-tile.
//
// R4 post-mortem: conflicts==0 but MfmaUtil 43% -> schedule-bound, 4990
// cyc/tile vs 2483 MFMA floor.  Fixes: (1) 32x32x16 MFMA (2495 vs 2075 TF
// ceiling, half the instructions); (2) hazard-minimal sync.
//
// LDS: [dbuf][row-half][128 rows][64 cols] bf16, slot' = slot ^ (row&7)
// swizzle (R4-verified: SQ_LDS_BANK_CONFLICT == 0), applied on global source
// (global_load_lds writes linearly) + on ds_read (both-sides involution).
//
// Per K-tile t (cur = t&1), phase c in {0,1} = k-chunk of 32:
//   ph(c): ds_read A x8 + B x4 (chunk c)       [no barrier, no waits: only
//          16x mfma_32x32x16 (chunk c)          own-register deps -> compiler
//                                               emits fine-grained lgkmcnt]
//   ph1 extras, between reads and MFMA:
//          lgkmcnt(0)+vmcnt(0); s_barrier;      <- THE one barrier
//          stage A(t+2),B(t+2) -> [cur] (8 global_load_lds, in MFMA shadow)
//
// Cross-wave hazard ledger (why one barrier suffices):
//  - Stage into [cur] must follow ALL waves' reads of [cur] (ph0+ph1):
//    each wave drains own reads (lgkm0) before the barrier; stages are
//    issued after it.  OK.
//  - t+1 reads of [nxt] need all waves' A(t+1),B(t+1) DMAs landed: each
//    wave vmcnt(0)-drains own DMAs before the same barrier.  OK.
//  - ph0 has no cross-wave hazard at all (read-read on [cur], staged >=1
//    tile ago and drained at t-1's barrier) -> no barrier needed.
//  - Wave skew is bounded by the per-tile barrier; a fast wave only ever
//    performs reads of [cur] early (safe).
//  - vmcnt(0) issue-to-wait slack: DMAs issued at t-1.ph1 post-barrier,
//    waited at t.ph1 pre-barrier ~ 1 MFMA cluster + full ph0 + ph1 reads
//    (~1600+ cyc) >> 900 cyc HBM latency -> no stall despite count 0.
//  - Tail tiles stage wrapped dummy slabs (never read; buffers dead).
// ============================================================================

__device__ __forceinline__ bf16x8 read_frag(const unsigned short* hb, int rowl, int slot) {
    int cs = slot ^ (rowl & 7);              // 3-bit XOR: all 8 bank-quads
    return *(const bf16x8*)(hb + rowl * 64 + (cs << 3));
}

__device__ __forceinline__ void stage_half(const unsigned short* __restrict__ G,
                                           int grow0, int K, int kbase,
                                           unsigned short* hb, int tid) {
    const int lane = tid & 63, wv = tid >> 6;
    #pragma unroll
    for (int j = 0; j < 2; ++j) {
        int u = j * 512 + wv * 64 + lane;            // 16B-unit 0..1023
        int rowl = u >> 3;
        int c = (u & 7) ^ (rowl & 7);                // inverse swizzle on source
        const unsigned short* g = G + (size_t)(grow0 + rowl) * K + kbase + c * 8;
        unsigned short* l = hb + (size_t)(j * 512 + wv * 64) * 8;  // wave-uniform
        __builtin_amdgcn_global_load_lds(
            (const __attribute__((address_space(1))) void*)g,
            (__attribute__((address_space(3))) void*)l, 16, 0, 0);
    }
}

__global__ __launch_bounds__(512, 2) void gemm_bt_bias(
    const unsigned short* __restrict__ A,   // bf16 bits [M,K]
    const unsigned short* __restrict__ B,   // bf16 bits [N,K] (weight)
    const float* __restrict__ bias,         // [N]
    float* __restrict__ C,                  // [M,N]
    int M, int N, int K)
{
    __shared__ unsigned short sA[2][2][8192];   // [dbuf][row-half][128*64]
    __shared__ unsigned short sB[2][2][8192];

    const int tid  = threadIdx.x;
    const int lane = tid & 63;
    const int wave = tid >> 6;
    const int wm = (wave >> 2) * 128;      // 2 waves along M
    const int wn = (wave & 3) * 64;        // 4 waves along N
    const int m32 = lane & 31;
    const int h   = lane >> 5;
    const int ah  = wm >> 7;               // wave's A row-half
    const int bh  = wn >> 7;               // wave's B row-half
    const int bro = wn & 64;               // row offset within B half

    // XCD-aware bijective remap (nwg = 512, %8 == 0)
    const int nbx = gridDim.x;
    const int nwg = gridDim.x * gridDim.y;
    int flat = blockIdx.y * gridDim.x + blockIdx.x;
    int rid = (nwg & 7) ? flat : ((flat & 7) * (nwg >> 3) + (flat >> 3));
    const int bm = (rid / nbx) * 256;
    const int bn = (rid % nbx) * 256;

    f32x16 acc[4][2];
    #pragma unroll
    for (int i = 0; i < 4; ++i)
        #pragma unroll
        for (int j = 0; j < 2; ++j)
            #pragma unroll
            for (int r = 0; r < 16; ++r) acc[i][j][r] = 0.f;

    // ---- prologue: tiles 0 and 1 for both operands ----
    stage_half(A, bm,       K, 0,  &sA[0][0][0], tid);
    stage_half(A, bm + 128, K, 0,  &sA[0][1][0], tid);
    stage_half(B, bn,       K, 0,  &sB[0][0][0], tid);
    stage_half(B, bn + 128, K, 0,  &sB[0][1][0], tid);
    stage_half(A, bm,       K, 64, &sA[1][0][0], tid);
    stage_half(A, bm + 128, K, 64, &sA[1][1][0], tid);
    stage_half(B, bn,       K, 64, &sB[1][0][0], tid);
    stage_half(B, bn + 128, K, 64, &sB[1][1][0], tid);
    asm volatile("s_waitcnt vmcnt(8)" ::: "memory");   // tile 0 landed
    __builtin_amdgcn_s_barrier();

    const int nt = K >> 6;
    for (int t = 0; t < nt; ++t) {
        const int cur = t & 1;
        const int t2k = ((t + 2 < nt) ? t + 2 : 0) << 6;   // wrap = dummy
        const unsigned short* sAh = &sA[cur][ah][0];
        const unsigned short* sBh = &sB[cur][bh][0];

        // ================= phase 0: k-chunk 0 (slots h, 2+h) ==============
        {
            bf16x8 a0[4], a1[4], b0[2], b1[2];
            #pragma unroll
            for (int i = 0; i < 4; ++i) {
                int rl = i * 32 + m32;
                a0[i] = read_frag(sAh, rl, h);
                a1[i] = read_frag(sAh, rl, 2 + h);
            }
            #pragma unroll
            for (int j = 0; j < 2; ++j) {
                int rl = bro + j * 32 + m32;
                b0[j] = read_frag(sBh, rl, h);
                b1[j] = read_frag(sBh, rl, 2 + h);
            }
            __builtin_amdgcn_s_setprio(1);
            #pragma unroll
            for (int i = 0; i < 4; ++i)
                #pragma unroll
                for (int j = 0; j < 2; ++j)
                    acc[i][j] = __builtin_amdgcn_mfma_f32_32x32x16_bf16(a0[i], b0[j], acc[i][j], 0, 0, 0);
            #pragma unroll
            for (int i = 0; i < 4; ++i)
                #pragma unroll
                for (int j = 0; j < 2; ++j)
                    acc[i][j] = __builtin_amdgcn_mfma_f32_32x32x16_bf16(a1[i], b1[j], acc[i][j], 0, 0, 0);
            __builtin_amdgcn_s_setprio(0);
        }

        // ================= phase 1: k-chunk 1 (slots 4+h, 6+h) ============
        {
            bf16x8 a0[4], a1[4], b0[2], b1[2];
            #pragma unroll
            for (int i = 0; i < 4; ++i) {
                int rl = i * 32 + m32;
                a0[i] = read_frag(sAh, rl, 4 + h);
                a1[i] = read_frag(sAh, rl, 6 + h);
            }
            #pragma unroll
            for (int j = 0; j < 2; ++j) {
                int rl = bro + j * 32 + m32;
                b0[j] = read_frag(sBh, rl, 4 + h);
                b1[j] = read_frag(sBh, rl, 6 + h);
            }
            // drain own ds_reads (cross-wave: stages below write [cur]) and
            // own DMAs (cross-wave: t+1 reads [nxt]) before THE barrier.
            asm volatile("s_waitcnt vmcnt(0) lgkmcnt(0)" ::: "memory");
            __builtin_amdgcn_sched_barrier(0);
            __builtin_amdgcn_s_barrier();
            // stages in the MFMA shadow (issued after barrier => all waves
            // done reading [cur]; landing checked at t+1's vmcnt)
            stage_half(A, bm,       K, t2k, &sA[cur][0][0], tid);
            stage_half(A, bm + 128, K, t2k, &sA[cur][1][0], tid);
            stage_half(B, bn,       K, t2k, &sB[cur][0][0], tid);
            stage_half(B, bn + 128, K, t2k, &sB[cur][1][0], tid);
            __builtin_amdgcn_s_setprio(1);
            #pragma unroll
            for (int i = 0; i < 4; ++i)
                #pragma unroll
                for (int j = 0; j < 2; ++j)
                    acc[i][j] = __builtin_amdgcn_mfma_f32_32x32x16_bf16(a0[i], b0[j], acc[i][j], 0, 0, 0);
            #pragma unroll
            for (int i = 0; i < 4; ++i)
                #pragma unroll
                for (int j = 0; j < 2; ++j)
                    acc[i][j] = __builtin_amdgcn_mfma_f32_32x32x16_bf16(a1[i], b1[j], acc[i][j], 0, 0, 0);
            __builtin_amdgcn_s_setprio(0);
        }
    }
    asm volatile("s_waitcnt vmcnt(0)" ::: "memory");   // drain dummy tail DMAs

    // ---- epilogue: 32x32 C/D layout col=lane&31, row=(r&3)+8*(r>>2)+4*h ----
    #pragma unroll
    for (int j = 0; j < 2; ++j) {
        int col = bn + wn + j * 32 + m32;
        float bv = bias[col];
        #pragma unroll
        for (int i = 0; i < 4; ++i) {
            int rbase = bm + wm + i * 32 + 4 * h;
            #pragma unroll
            for (int r = 0; r < 16; ++r) {
                int row = rbase + (r & 3) + 8 * (r >> 2);
                __builtin_nontemporal_store(acc[i][j][r] + bv,
                                            &C[(size_t)row * N + col]);
            }
        }
    }
}

extern "C" void kernel_launch(void* const* d_in, const int* in_sizes, int n_in,
                              void* d_out, int out_size, void* d_ws, size_t ws_size,
                              hipStream_t stream) {
    const float* vals   = (const float*)d_in[0];
    const int*   rows   = (const int*)d_in[1];
    const int*   cols   = (const int*)d_in[2];
    const float* weight = (const float*)d_in[3];  // [OUT, IN] row-major
    const float* bias   = (const float*)d_in[4];

    const int NNZ = in_sizes[0];
    const int OUT = in_sizes[4];
    const int IN  = in_sizes[3] / OUT;
    const int M   = out_size / OUT;     // n_rows

    // workspace layout: Ab bf16 [M,IN] | Wb bf16 [OUT,IN]
    unsigned short* Ab = (unsigned short*)d_ws;
    size_t abBytes = (size_t)M * IN * sizeof(unsigned short);
    unsigned short* Wb = (unsigned short*)((char*)d_ws + abBytes);

    // 1) zero bf16 dense (bf16 zero == 0x0000)
    hipMemsetAsync(Ab, 0, abBytes, stream);

    // 2+3) fused scatter-add (pk_add_bf16) + weight convert
    {
        long nW = (long)OUT * IN;
        int cvtBlocks = (int)((nW / 8 + 255) / 256);
        int scBlocks  = (NNZ + 255) / 256;
        scatter_cvt<<<cvtBlocks + scBlocks, 256, 0, stream>>>(
            vals, rows, cols, Ab, NNZ, IN, weight, Wb, nW, cvtBlocks);
    }

    // 4) GEMM + bias (256x256 tiles, 512 threads)
    dim3 grid(OUT / 256, M / 256);   // 16 x 32 = 512 blocks
    gemm_bt_bias<<<grid, 512, 0, stream>>>(Ab, Wb, bias, (float*)d_out, M, OUT, IN);
}